// Round 10
// baseline (408.856 us; speedup 1.0000x reference)
//
#include <hip/hip_runtime.h>
#include <math.h>

// Problem constants
#define B_ 16
#define C_ 64
#define H_ 128
#define W_ 128
#define HW_ (H_*W_)
#define OUT_ELEMS 16777216   // B*C*H*W

// Workspace byte offsets
#define CHM_B    0                      // 512 f32
#define PWA_B    2048                   // 16384 u16
#define AH_B     34816                  // 258048 u16
#define FEA_B(s) (550912u + (size_t)(s)*33554432u)  // 4 x 16777216 u16
// fea layout from round-10 on: NHWC  [b][h][w][c], c=64 contiguous (128B/px)

// A-image u16 offsets within AH
#define A_S0   0
#define A_S(s) (36864 + ((s)-1)*73728)  // s = 1..3

// conv0 LDS sub-tile (r9-verified NCHW staging path): 3 x 130 x 36 u16
#define SUBT 14040

typedef __attribute__((ext_vector_type(4))) short  v4s;
typedef __attribute__((ext_vector_type(8))) short  v8s;
typedef __attribute__((ext_vector_type(4))) float  v4f;

__device__ __forceinline__ ushort f2bf(float f) {
    unsigned u = __builtin_bit_cast(unsigned, f);
    unsigned r = u + 0x7FFFu + ((u >> 16) & 1u);
    return (ushort)(r >> 16);
}

// ---------------------------------------------------------------------------
__global__ __launch_bounds__(64) void mask_kernel(
    const float* __restrict__ gum, const float* __restrict__ par,
    float* __restrict__ chm, float* __restrict__ out_tail)
{
    int c = threadIdx.x;
    #pragma unroll
    for (int i = 0; i < 4; ++i) {
        int base = (c*4 + i)*2;
        float g0 = -logf(-logf(gum[base]));
        float g1 = -logf(-logf(gum[base+1]));
        float a0 = par[base] + g0, a1 = par[base+1] + g1;
        float mx = fmaxf(a0, a1);
        float e0 = expf(a0 - mx), e1 = expf(a1 - mx);
        float inv = 1.0f / (e0 + e1);
        float m0 = e0*inv, m1 = e1*inv;
        chm[base] = m0; chm[base+1] = m1;
        out_tail[base] = m0; out_tail[base+1] = m1;
    }
}

// ---------------------------------------------------------------------------
// Build bf16 A-images (gate-folded weights) + bf16 pw weights. (unchanged)
__global__ __launch_bounds__(256) void prep_kernel(
    const float* __restrict__ w0, const float* __restrict__ w1,
    const float* __restrict__ w2, const float* __restrict__ w3,
    const float* __restrict__ wc, const float* __restrict__ chm,
    ushort* __restrict__ AH, ushort* __restrict__ pwA)
{
    int idx = blockIdx.x*256 + threadIdx.x;   // < 274432
    if (idx < 36864) {
        int blk = idx >> 11;            // c*9+t, 0..17
        int r3  = idx & 2047;
        int oc = r3 >> 5, icl = r3 & 31;
        int cc = blk / 9, t = blk - 9*cc;
        int ic = cc*32 + icl;
        AH[idx] = f2bf(w0[(oc*64 + ic)*9 + t]);
    } else if (idx < 258048) {
        int j = idx - 36864;
        int s = 1 + j / 73728;
        int r = j % 73728;
        int blk = r >> 12;              // 0..17
        int r3  = r & 4095;
        int ocM = r3 >> 5, icl = r3 & 31;
        int cc = blk / 9, t = blk - 9*cc;
        int ic = cc*32 + icl;
        int oc = ocM >> 1, set = ocM & 1;
        const float* wsrc = (s == 1) ? w1 : (s == 2 ? w2 : w3);
        AH[idx] = f2bf(wsrc[(oc*64 + ic)*9 + t] * chm[(ic*4 + s)*2 + set]);
    } else {
        int r = idx - 258048;           // < 16384
        pwA[r] = f2bf(wc[r]);
    }
}

// ---------------------------------------------------------------------------
// Stage-0 conv (x0 NCHW f32 input -> fea0 NHWC bf16 output).
// Body = r9-verified kernel (single-phase, 36-stride swizzled LDS, reg
// staging transpose, A ring-4, B ring-3); ONLY the epilogue store address
// changed to NHWC. NSETS=1 / INF32 only instantiation.
template<int NSETS, bool INF32>
__global__ __launch_bounds__(256, 2) void conv_bf16(
    const void* __restrict__ inv, const ushort* __restrict__ A,
    const float* __restrict__ chm, const float* __restrict__ spa,
    ushort* __restrict__ feaOut, int stage)
{
    constexpr int MOC = 64*NSETS;
    constexpr int MT  = MOC/32;
    __shared__ __align__(16) ushort sB[2*SUBT]; // 56160 B

    const int tid  = threadIdx.x;
    const int lane = tid & 63, wave = tid >> 6;
    const int wrow = wave >> 1, wcol = wave & 1;
    const int q = lane >> 4, ln16 = lane & 15;
    const int wk = (blockIdx.x & 7)*256 + (blockIdx.x >> 3);
    const int h = wk & 127, b = wk >> 7;

    v4f acc[MT][4];
    #pragma unroll
    for (int m = 0; m < MT; ++m)
        #pragma unroll
        for (int n = 0; n < 4; ++n) acc[m][n] = (v4f){0.f, 0.f, 0.f, 0.f};

    int aRow[MT];
    #pragma unroll
    for (int m = 0; m < MT; ++m)
        aRow[m] = (wrow*(MOC/2) + m*16 + ln16)*32 + q*8;

    v8s stg[12];
    v4f stgF[24];
    v8s af[4][MT];

    auto issue = [&](int c) {
        const int ic0 = c*32;
        #pragma unroll
        for (int it = 0; it < 6; ++it) {
            int i  = it*256 + tid;
            int ry = i >> 9;
            int r  = i & 511;
            int ic = r >> 4, wv = r & 15;
            int gh = h - 1 + ry;
            if constexpr (INF32) {
                v4f a0 = (v4f){0.f,0.f,0.f,0.f}, a1 = a0;
                if ((unsigned)gh < 128u) {
                    const float* s = (const float*)inv +
                        ((size_t)((b*C_ + ic0 + ic)*H_ + gh)*W_ + wv*8);
                    a0 = *(const v4f*)(const void*)s;
                    a1 = *(const v4f*)(const void*)(s + 4);
                }
                stgF[(c*6+it)*2] = a0; stgF[(c*6+it)*2+1] = a1;
            } else {
                v8s v = (v8s){0,0,0,0,0,0,0,0};
                if ((unsigned)gh < 128u)
                    v = *(const v8s*)(const void*)((const ushort*)inv +
                        ((size_t)((b*C_ + ic0 + ic)*H_ + gh)*W_ + wv*8));
                stg[c*6+it] = v;
            }
        }
    };
    auto scatter = [&](int c) {
        ushort* sBc = sB + c*SUBT;
        #pragma unroll
        for (int it = 0; it < 6; ++it) {
            int i  = it*256 + tid;
            int ry = i >> 9;
            int r  = i & 511;
            int ic = r >> 4, wv = r & 15;
            int colBase = ry*130 + wv*8 + 1;
            ushort vals[8];
            if constexpr (INF32) {
                #pragma unroll
                for (int j = 0; j < 4; ++j) {
                    vals[j]   = f2bf(stgF[(c*6+it)*2][j]);
                    vals[4+j] = f2bf(stgF[(c*6+it)*2+1][j]);
                }
            } else {
                #pragma unroll
                for (int j = 0; j < 8; ++j) vals[j] = (ushort)stg[c*6+it][j];
            }
            #pragma unroll
            for (int j = 0; j < 8; ++j) {
                int colIdx = colBase + j;
                int s3 = (colIdx >> 3) & 7;
                sBc[colIdx*36 + (ic ^ (s3 << 2))] = vals[j];
            }
        }
    };
    auto prolog = [&]() {
        #pragma unroll
        for (int tp = 0; tp < 3; ++tp)
            #pragma unroll
            for (int m = 0; m < MT; ++m)
                af[tp][m] = *(const v8s*)(const void*)(A + tp*MOC*32 + aRow[m]);
    };
    auto loadB = [&](int tt, v8s* dst) {
        const int c  = tt/9, t = tt - 9*c;
        const int ky = t/3, kx = t - 3*(t/3);
        const ushort* sBc = sB + c*SUBT;
        #pragma unroll
        for (int nt = 0; nt < 4; ++nt) {
            int colIdx = ky*130 + wcol*64 + nt*16 + ln16 + kx;
            int s3 = (colIdx >> 3) & 7;
            int base = colIdx*36 + ((q ^ (s3 >> 1)) << 3);
            int lo = base + ((s3 & 1) << 2);
            int hi = base + (((s3 & 1) ^ 1) << 2);
            v4s va = *(const v4s*)(const void*)(sBc + lo);
            v4s vb = *(const v4s*)(const void*)(sBc + hi);
            dst[nt] = __builtin_shufflevector(va, vb, 0, 1, 2, 3, 4, 5, 6, 7);
        }
    };

    issue(0);
    issue(1);
    prolog();
    if (tid < 216) {
        int colSel = tid / 36;
        int icz    = tid - colSel*36;
        int ry     = colSel >> 1;
        int colIdx = ry*130 + ((colSel & 1) ? 129 : 0);
        sB[colIdx*36 + icz] = 0;
        sB[SUBT + colIdx*36 + icz] = 0;
    }
    scatter(0);
    scatter(1);
    __syncthreads();

    v8s bf[3][4];
    loadB(0, bf[0]);
    loadB(1, bf[1]);
    #pragma unroll
    for (int tt = 0; tt < 18; ++tt) {
        if (tt < 16) loadB(tt+2, bf[(tt+2)%3]);
        if (tt < 15) {
            #pragma unroll
            for (int m = 0; m < MT; ++m)
                af[(tt+3)&3][m] = *(const v8s*)(const void*)(A + (tt+3)*MOC*32 + aRow[m]);
        }
        #pragma unroll
        for (int nt = 0; nt < 4; ++nt)
            #pragma unroll
            for (int m = 0; m < MT; ++m)
                acc[m][nt] = __builtin_amdgcn_mfma_f32_16x16x32_bf16(af[tt&3][m], bf[tt%3][nt], acc[m][nt], 0, 0, 0);
    }

    // epilogue: gates + relu, bf16 store -> NHWC  ((b,h,w) major, c fastest)
    const float* spaRow = &spa[b*HW_ + h*W_];
    const size_t rowBase = ((size_t)(b*H_ + h))*W_;
    #pragma unroll
    for (int nt = 0; nt < 4; ++nt) {
        int px = wcol*64 + nt*16 + ln16;
        float sp = spaRow[px];
        #pragma unroll
        for (int m = 0; m < MT; ++m) {
            if constexpr (NSETS == 2) {
                #pragma unroll
                for (int rp = 0; rp < 2; ++rp) {
                    int oc = wrow*32 + m*8 + q*2 + rp;
                    float md = chm[(oc*4 + stage)*2 + 0];
                    float ms = chm[(oc*4 + stage)*2 + 1];
                    float f = acc[m][nt][2*rp]*(ms*sp + md)
                            + acc[m][nt][2*rp+1]*((ms + md)*sp);
                    feaOut[(rowBase + px)*64 + oc] = f2bf(fmaxf(f, 0.f));
                }
            } else {
                #pragma unroll
                for (int r = 0; r < 4; ++r) {
                    int oc = wrow*32 + m*16 + q*4 + r;
                    float md = chm[(oc*4 + stage)*2 + 0];
                    float ms = chm[(oc*4 + stage)*2 + 1];
                    float f = acc[m][nt][r]*(ms*sp + md);
                    feaOut[(rowBase + px)*64 + oc] = f2bf(fmaxf(f, 0.f));
                }
            }
        }
    }
}

// ---------------------------------------------------------------------------
// Stages 1-3 conv: NHWC bf16 in -> NHWC bf16 out. M=128 ocM, N=128 px, K=64.
// NHWC kills the transpose: staging = 12 v8s loads + 12 linear b128 LDS
// stores per thread (was 12 loads + 96 scalar scatter stores, 4-way
// conflicts). Swizzle moved to the SOURCE address (involution): LDS slot
// (col, grp) holds global ic-group grp^(col&7); reads compute the same XOR
// -> single ds_read_b128, 2 lanes/bank (free). One LDS tile holds all 64 ic
// (3 x 130 x 64 u16 = 49920 B); 9 tap-steps x 2 k-halves x 16 MFMA.
// A-image layout unchanged (chunk kk <-> ic-half). A ring-2 prefetch.
__global__ __launch_bounds__(256, 2) void conv_nhwc(
    const ushort* __restrict__ fin, const ushort* __restrict__ A,
    const float* __restrict__ chm, const float* __restrict__ spa,
    ushort* __restrict__ feaOut, int stage)
{
    __shared__ __align__(16) ushort sB[3*130*64];   // 49920 B

    const int tid  = threadIdx.x;
    const int lane = tid & 63, wave = tid >> 6;
    const int wrow = wave >> 1, wcol = wave & 1;
    const int q = lane >> 4, ln16 = lane & 15;
    const int wk = (blockIdx.x & 7)*256 + (blockIdx.x >> 3);
    const int h = wk & 127, b = wk >> 7;
    const size_t rowBase = ((size_t)(b*H_ + h))*W_;

    v4f acc[4][4];
    #pragma unroll
    for (int m = 0; m < 4; ++m)
        #pragma unroll
        for (int n = 0; n < 4; ++n) acc[m][n] = (v4f){0.f, 0.f, 0.f, 0.f};

    int aRow[4];
    #pragma unroll
    for (int m = 0; m < 4; ++m)
        aRow[m] = (wrow*64 + m*16 + ln16)*32 + q*8;

    // ---- staging: issue 12 x v8s (NHWC: ic contiguous, no transpose) ----
    v8s stg[12];
    #pragma unroll
    for (int it = 0; it < 12; ++it) {
        int i   = it*256 + tid;      // [0, 3072)
        int ry  = i >> 10;           // 0..2
        int r   = i & 1023;
        int col = r >> 3, grp = r & 7;
        int gh  = h - 1 + ry;
        v8s v = (v8s){0,0,0,0,0,0,0,0};
        if ((unsigned)gh < 128u) {
            int icg = grp ^ ((col + 1) & 7);   // source pre-swizzle (involution)
            v = *(const v8s*)(const void*)(fin +
                (((size_t)(b*H_ + gh))*W_ + col)*64 + icg*8);
        }
        stg[it] = v;
    }
    // halo cols {0,129} of all 3 rows: zero (disjoint from stores: cols 1..128)
    if (tid < 48) {
        int ry = tid >> 4, k = tid & 15;
        int colIdx = (k & 8) ? 129 : 0;
        int grp = k & 7;
        *(v8s*)(void*)(sB + (ry*130 + colIdx)*64 + grp*8) = (v8s){0,0,0,0,0,0,0,0};
    }
    // ---- linear b128 stores (zero conflicts; OOB rows store zeros) ----
    #pragma unroll
    for (int it = 0; it < 12; ++it) {
        int i   = it*256 + tid;
        int ry  = i >> 10;
        int r   = i & 1023;
        int col = r >> 3, grp = r & 7;
        *(v8s*)(void*)(sB + (ry*130 + col + 1)*64 + grp*8) = stg[it];
    }
    __syncthreads();

    // ---- compute: 9 taps x {kk=0,1} ; A ring-2 ----
    v8s af[2][2][4];
    #pragma unroll
    for (int kk = 0; kk < 2; ++kk)
        #pragma unroll
        for (int m = 0; m < 4; ++m)
            af[0][kk][m] = *(const v8s*)(const void*)(A + (size_t)(kk*9 + 0)*4096 + aRow[m]);

    #pragma unroll
    for (int t = 0; t < 9; ++t) {
        if (t < 8) {
            #pragma unroll
            for (int kk = 0; kk < 2; ++kk)
                #pragma unroll
                for (int m = 0; m < 4; ++m)
                    af[(t+1)&1][kk][m] = *(const v8s*)(const void*)(A + (size_t)(kk*9 + t+1)*4096 + aRow[m]);
        }
        const int ky = t/3, kx = t - 3*(t/3);
        v8s bf[2][4];
        #pragma unroll
        for (int nt = 0; nt < 4; ++nt) {
            int col2 = wcol*64 + nt*16 + ln16 + kx;    // 0..129
            int key  = col2 & 7;
            #pragma unroll
            for (int kk = 0; kk < 2; ++kk) {
                int grp = (kk*4 + q) ^ key;
                bf[kk][nt] = *(const v8s*)(const void*)(sB + (ky*130 + col2)*64 + grp*8);
            }
        }
        #pragma unroll
        for (int nt = 0; nt < 4; ++nt)
            #pragma unroll
            for (int kk = 0; kk < 2; ++kk)
                #pragma unroll
                for (int m = 0; m < 4; ++m)
                    acc[m][nt] = __builtin_amdgcn_mfma_f32_16x16x32_bf16(af[t&1][kk][m], bf[kk][nt], acc[m][nt], 0, 0, 0);
    }

    // ---- epilogue: gates + relu -> NHWC bf16 ----
    const float* spaRow = &spa[b*HW_ + h*W_];
    #pragma unroll
    for (int nt = 0; nt < 4; ++nt) {
        int px = wcol*64 + nt*16 + ln16;
        float sp = spaRow[px];
        #pragma unroll
        for (int m = 0; m < 4; ++m) {
            #pragma unroll
            for (int rp = 0; rp < 2; ++rp) {
                int oc = wrow*32 + m*8 + q*2 + rp;
                float md = chm[(oc*4 + stage)*2 + 0];
                float ms = chm[(oc*4 + stage)*2 + 1];
                float f = acc[m][nt][2*rp]*(ms*sp + md)
                        + acc[m][nt][2*rp+1]*((ms + md)*sp);
                feaOut[(rowBase + px)*64 + oc] = f2bf(fmaxf(f, 0.f));
            }
        }
    }
}

// ---------------------------------------------------------------------------
// Final pointwise, NHWC fea inputs. out stays NCHW f32.
// sF layout [s][px][ic] u16 (32 KB), source-swizzled like conv_nhwc:
// slot (px, grp) holds ic-group grp^(px&7). Staging = 8 v8s loads + 8 linear
// b128 stores (was 8 loads + 64 scalar scatter stores). Read = single b128.
__global__ __launch_bounds__(256, 2) void pw_final(
    const ushort* __restrict__ fea, const ushort* __restrict__ pwA,
    const float* __restrict__ bc, float* __restrict__ out)
{
    __shared__ __align__(16) ushort sF[4*64*64];   // 32768 B

    const int tid  = threadIdx.x;
    const int lane = tid & 63, wave = tid >> 6;
    const int wrow = wave >> 1, wcol = wave & 1;
    const int q = lane >> 4, ln16 = lane & 15;
    const int half = blockIdx.x & 1;
    const int h = (blockIdx.x >> 1) & 127;
    const int b = blockIdx.x >> 8;
    const int px0 = half*64;

    {
        v8s stg[8];
        #pragma unroll
        for (int it = 0; it < 8; ++it) {
            int i  = it*256 + tid;   // [0,2048)
            int s  = i >> 9;
            int r  = i & 511;
            int px = r >> 3, grp = r & 7;
            int icg = grp ^ (px & 7);
            stg[it] = *(const v8s*)(const void*)(
                fea + (size_t)s*OUT_ELEMS +
                (((size_t)(b*H_ + h))*W_ + px0 + px)*64 + icg*8);
        }
        #pragma unroll
        for (int it = 0; it < 8; ++it) {
            int i  = it*256 + tid;
            int s  = i >> 9;
            int r  = i & 511;
            int px = r >> 3, grp = r & 7;
            *(v8s*)(void*)(sF + (s*64 + px)*64 + grp*8) = stg[it];
        }
    }
    __syncthreads();

    v4f acc[2][2];
    #pragma unroll
    for (int m = 0; m < 2; ++m)
        #pragma unroll
        for (int n = 0; n < 2; ++n) acc[m][n] = (v4f){0.f, 0.f, 0.f, 0.f};

    #pragma unroll
    for (int ks = 0; ks < 8; ++ks) {
        v8s a[2];
        #pragma unroll
        for (int m = 0; m < 2; ++m)
            a[m] = *(const v8s*)(const void*)(pwA + (wrow*32 + m*16 + ln16)*256 + ks*32 + q*8);
        #pragma unroll
        for (int n = 0; n < 2; ++n) {
            int px = wcol*32 + n*16 + ln16;
            int s  = ks >> 1;
            int grp = ((ks & 1)*4 + q) ^ (px & 7);
            v8s bf = *(const v8s*)(const void*)(sF + (s*64 + px)*64 + grp*8);
            #pragma unroll
            for (int m = 0; m < 2; ++m)
                acc[m][n] = __builtin_amdgcn_mfma_f32_16x16x32_bf16(a[m], bf, acc[m][n], 0, 0, 0);
        }
    }

    #pragma unroll
    for (int n = 0; n < 2; ++n) {
        int px = px0 + wcol*32 + n*16 + ln16;
        #pragma unroll
        for (int m = 0; m < 2; ++m)
            #pragma unroll
            for (int r = 0; r < 4; ++r) {
                int o = wrow*32 + m*16 + q*4 + r;
                out[((size_t)(b*C_ + o)*H_ + h)*W_ + px] = acc[m][n][r] + bc[o];
            }
    }
}

// ---------------------------------------------------------------------------
extern "C" void kernel_launch(void* const* d_in, const int* in_sizes, int n_in,
                              void* d_out, int out_size, void* d_ws, size_t ws_size,
                              hipStream_t stream)
{
    const float* x0  = (const float*)d_in[0];
    const float* spa = (const float*)d_in[1];
    const float* gum = (const float*)d_in[2];
    const float* par = (const float*)d_in[3];
    const float* w0  = (const float*)d_in[4];
    const float* w1  = (const float*)d_in[5];
    const float* w2  = (const float*)d_in[6];
    const float* w3  = (const float*)d_in[7];
    const float* wc  = (const float*)d_in[8];
    const float* bc  = (const float*)d_in[9];
    float* out = (float*)d_out;
    char*  ws  = (char*)d_ws;

    float*  chm = (float*)(ws + CHM_B);
    ushort* pwA = (ushort*)(ws + PWA_B);
    ushort* AH  = (ushort*)(ws + AH_B);
    ushort* fea0 = (ushort*)(ws + FEA_B(0));
    ushort* fea1 = (ushort*)(ws + FEA_B(1));
    ushort* fea2 = (ushort*)(ws + FEA_B(2));
    ushort* fea3 = (ushort*)(ws + FEA_B(3));

    mask_kernel<<<1, 64, 0, stream>>>(gum, par, chm, out + OUT_ELEMS);
    prep_kernel<<<1072, 256, 0, stream>>>(w0, w1, w2, w3, wc, chm, AH, pwA);

    conv_bf16<1, true><<<2048, 256, 0, stream>>>(x0, AH + A_S0, chm, spa, fea0, 0);
    conv_nhwc<<<2048, 256, 0, stream>>>(fea0, AH + A_S(1), chm, spa, fea1, 1);
    conv_nhwc<<<2048, 256, 0, stream>>>(fea1, AH + A_S(2), chm, spa, fea2, 2);
    conv_nhwc<<<2048, 256, 0, stream>>>(fea2, AH + A_S(3), chm, spa, fea3, 3);

    pw_final<<<4096, 256, 0, stream>>>(fea0, pwA, bc, out);
}